// Round 5
// baseline (1292.945 us; speedup 1.0000x reference)
//
#include <hip/hip_runtime.h>
#include <stdint.h>

typedef __attribute__((ext_vector_type(4))) float f32x4;
typedef __attribute__((ext_vector_type(8))) short bf16x8;

#define MFMA_BF16 __builtin_amdgcn_mfma_f32_16x16x32_bf16

__device__ __forceinline__ unsigned short f2bf(float f) {
  union { float f; uint32_t u; } a; a.f = f;
  uint32_t u = a.u;
  uint32_t r = (u + 0x7FFFu + ((u >> 16) & 1u)) >> 16;
  return (unsigned short)r;
}

// Pack [x | h] -> bf16 A[4096][4096] row-major (K = IN(2048) then H(2048))
__global__ void pack_a_kernel(const float4* __restrict__ x, const float4* __restrict__ hh,
                              ushort4* __restrict__ A) {
  const int total = 4096 * 1024;
  for (int q = blockIdx.x * blockDim.x + threadIdx.x; q < total; q += gridDim.x * blockDim.x) {
    int row = q >> 10, cq = q & 1023;
    float4 v = (cq < 512) ? x[row * 512 + cq] : hh[row * 512 + (cq - 512)];
    ushort4 o; o.x = f2bf(v.x); o.y = f2bf(v.y); o.z = f2bf(v.z); o.w = f2bf(v.w);
    A[q] = o;
  }
}

// Pack 8 weight mats -> bf16 Wp[8192][4096].
// Packed row p: bn=p>>8, r=p&255; half=r>>7, wn=(r>>5)&3, glow=(r>>4)&1, hlow=r&15
//   gate g = half*2+glow ; hcol H = bn*64 + wn*16 + hlow
// cols 0..2047 = Wx_g[H][:], 2048..4095 = Wh_g[H][:]
__global__ void pack_w_kernel(const float* __restrict__ Wii, const float* __restrict__ Wif,
                              const float* __restrict__ Wig, const float* __restrict__ Wio,
                              const float* __restrict__ Whi, const float* __restrict__ Whf,
                              const float* __restrict__ Whg, const float* __restrict__ Who,
                              ushort4* __restrict__ Wp) {
  const int total = 8192 * 1024;
  for (int q = blockIdx.x * blockDim.x + threadIdx.x; q < total; q += gridDim.x * blockDim.x) {
    int p = q >> 10, kq = q & 1023;
    int r = p & 255;
    int g = ((r >> 7) << 1) | ((r >> 4) & 1);
    int H = ((p >> 8) << 6) | (((r >> 5) & 3) << 4) | (r & 15);
    const float* src;
    if (kq < 512) src = (g == 0) ? Wii : (g == 1) ? Wif : (g == 2) ? Wig : Wio;
    else          src = (g == 0) ? Whi : (g == 1) ? Whf : (g == 2) ? Whg : Who;
    const float4 v = *(const float4*)&src[(size_t)H * 2048 + ((kq & 511) << 2)];
    ushort4 o; o.x = f2bf(v.x); o.y = f2bf(v.y); o.z = f2bf(v.z); o.w = f2bf(v.w);
    Wp[q] = o;
  }
}

// 256x256 tile, BK=64, 8 waves (2Mx4N), per-wave 128x64, 4 phases/tile,
// SOFTWARE-PIPELINED ds_reads (one phase ahead, compiler counted lgkmcnt),
// one barrier/phase, 2-tile-ahead same-buffer staging + counted vmcnt,
// T2 XOR-swizzle, T5 setprio, bn-major XCD mapping.
#define STG(srcbase, jj, koff, dstE)                                                        \
  __builtin_amdgcn_global_load_lds(                                                        \
      (const __attribute__((address_space(1))) void*)((srcbase) + (size_t)(jj)*262144 + (koff)), \
      (__attribute__((address_space(3))) void*)(&smem[(dstE) + (jj)*4096]), 16, 0, 0)

// One tile: 4 phases. MFMA consumes frags read in the previous phase;
// each phase issues reads for the next phase. Reads/phase: 4/8/8/4.
#define TILE_BODY(T_, bufE_, AF0c, BF01c, AF0n, BF01n)                                      \
  {                                                                                         \
    const int kS = ((T_) + 2) << 6;                                                         \
    const bool st = (T_) <= 61;                                                             \
    const bool rdn = (T_) < 63;                                                             \
    /* == ph0: read bf23(T,cur buf); MFMA af0c x bf01c -> acc[0..3][0..1] == */             \
    _Pragma("unroll") for (int n = 0; n < 2; ++n) {                                         \
      bf23_[n][0] = *(const bf16x8*)&smem[(bufE_) + bBase + 8192 + n * 1024 + colE0];       \
      bf23_[n][1] = *(const bf16x8*)&smem[(bufE_) + bBase + 8192 + n * 1024 + colE1];       \
    }                                                                                       \
    __builtin_amdgcn_s_setprio(1);                                                          \
    _Pragma("unroll") for (int m = 0; m < 4; ++m)                                           \
      _Pragma("unroll") for (int n = 0; n < 2; ++n) {                                       \
        acc[m][n] = MFMA_BF16(AF0c[m][0], BF01c[n][0], acc[m][n], 0, 0, 0);                 \
        acc[m][n] = MFMA_BF16(AF0c[m][1], BF01c[n][1], acc[m][n], 0, 0, 0);                 \
      }                                                                                     \
    __builtin_amdgcn_s_setprio(0);                                                          \
    if ((T_) < 63) asm volatile("s_waitcnt vmcnt(8)" ::: "memory");                         \
    else           asm volatile("s_waitcnt vmcnt(0)" ::: "memory");                         \
    __builtin_amdgcn_sched_barrier(0);                                                      \
    __builtin_amdgcn_s_barrier();                                                           \
    /* == ph1: read af1(T); STG A0B0(T+2); MFMA af0c x bf23 -> acc[0..3][2..3] == */        \
    _Pragma("unroll") for (int m = 0; m < 4; ++m) {                                         \
      af1_[m][0] = *(const bf16x8*)&smem[(bufE_) + aBase + 8192 + m * 1024 + colE0];        \
      af1_[m][1] = *(const bf16x8*)&smem[(bufE_) + aBase + 8192 + m * 1024 + colE1];        \
    }                                                                                       \
    if (st) {                                                                               \
      STG(aSrc, 0, kS, (bufE_) + aDstW); STG(aSrc, 1, kS, (bufE_) + aDstW);                 \
      STG(bSrc, 0, kS, (bufE_) + bDstW); STG(bSrc, 1, kS, (bufE_) + bDstW);                 \
    }                                                                                       \
    __builtin_amdgcn_s_setprio(1);                                                          \
    _Pragma("unroll") for (int m = 0; m < 4; ++m)                                           \
      _Pragma("unroll") for (int n = 0; n < 2; ++n) {                                       \
        acc[m][2 + n] = MFMA_BF16(AF0c[m][0], bf23_[n][0], acc[m][2 + n], 0, 0, 0);         \
        acc[m][2 + n] = MFMA_BF16(AF0c[m][1], bf23_[n][1], acc[m][2 + n], 0, 0, 0);         \
      }                                                                                     \
    __builtin_amdgcn_s_setprio(0);                                                          \
    if ((T_) < 62)       asm volatile("s_waitcnt vmcnt(8)" ::: "memory");                   \
    else if ((T_) == 62) asm volatile("s_waitcnt vmcnt(4)" ::: "memory");                   \
    __builtin_amdgcn_sched_barrier(0);                                                      \
    __builtin_amdgcn_s_barrier();                                                           \
    /* == ph2: read AF0n(T+1, other buf); STG B1(T+2); MFMA af1 x bf01c -> acc[4..7][0..1] */ \
    if (rdn) {                                                                              \
      _Pragma("unroll") for (int m = 0; m < 4; ++m) {                                       \
        AF0n[m][0] = *(const bf16x8*)&smem[((bufE_) ^ 32768) + aBase + m * 1024 + colE0];   \
        AF0n[m][1] = *(const bf16x8*)&smem[((bufE_) ^ 32768) + aBase + m * 1024 + colE1];   \
      }                                                                                     \
    }                                                                                       \
    if (st) { STG(bSrc, 2, kS, (bufE_) + bDstW); STG(bSrc, 3, kS, (bufE_) + bDstW); }       \
    __builtin_amdgcn_s_setprio(1);                                                          \
    _Pragma("unroll") for (int m = 0; m < 4; ++m)                                           \
      _Pragma("unroll") for (int n = 0; n < 2; ++n) {                                       \
        acc[4 + m][n] = MFMA_BF16(af1_[m][0], BF01c[n][0], acc[4 + m][n], 0, 0, 0);         \
        acc[4 + m][n] = MFMA_BF16(af1_[m][1], BF01c[n][1], acc[4 + m][n], 0, 0, 0);         \
      }                                                                                     \
    __builtin_amdgcn_s_setprio(0);                                                          \
    __builtin_amdgcn_sched_barrier(0);                                                      \
    __builtin_amdgcn_s_barrier();                                                           \
    /* == ph3: read BF01n(T+1); STG A1(T+2); MFMA af1 x bf23 -> acc[4..7][2..3] == */       \
    if (rdn) {                                                                              \
      _Pragma("unroll") for (int n = 0; n < 2; ++n) {                                       \
        BF01n[n][0] = *(const bf16x8*)&smem[((bufE_) ^ 32768) + bBase + n * 1024 + colE0];  \
        BF01n[n][1] = *(const bf16x8*)&smem[((bufE_) ^ 32768) + bBase + n * 1024 + colE1];  \
      }                                                                                     \
    }                                                                                       \
    if (st) { STG(aSrc, 2, kS, (bufE_) + aDstW); STG(aSrc, 3, kS, (bufE_) + aDstW); }       \
    __builtin_amdgcn_s_setprio(1);                                                          \
    _Pragma("unroll") for (int m = 0; m < 4; ++m)                                           \
      _Pragma("unroll") for (int n = 0; n < 2; ++n) {                                       \
        acc[4 + m][2 + n] = MFMA_BF16(af1_[m][0], bf23_[n][0], acc[4 + m][2 + n], 0, 0, 0); \
        acc[4 + m][2 + n] = MFMA_BF16(af1_[m][1], bf23_[n][1], acc[4 + m][2 + n], 0, 0, 0); \
      }                                                                                     \
    __builtin_amdgcn_s_setprio(0);                                                          \
    if ((T_) < 62)       asm volatile("s_waitcnt vmcnt(10)" ::: "memory");                  \
    else if ((T_) == 62) asm volatile("s_waitcnt vmcnt(2)" ::: "memory");                   \
    if ((T_) < 63) {                                                                        \
      __builtin_amdgcn_sched_barrier(0);                                                    \
      __builtin_amdgcn_s_barrier();                                                         \
    }                                                                                       \
  }

__global__ __launch_bounds__(512, 1)
void lstm_gemm_kernel(const ushort* __restrict__ A, const ushort* __restrict__ Wp,
                      const float* __restrict__ c,
                      const float* __restrict__ bii, const float* __restrict__ bif_,
                      const float* __restrict__ big_, const float* __restrict__ bio_,
                      const float* __restrict__ bhi, const float* __restrict__ bhf,
                      const float* __restrict__ bhg, const float* __restrict__ bho,
                      float* __restrict__ out) {
  __shared__ ushort smem[65536];  // 2 bufs x (A 256x64 + B 256x64) bf16 = 128 KiB
  const int tid = threadIdx.x;
  const int lane = tid & 63, w = tid >> 6;
  const int wm = w >> 2, wn = w & 3;

  // bn-major XCD mapping: XCD x owns bn in [x*4, x*4+4) x all 16 bm.
  const int bid = blockIdx.x;
  const int xcd = bid & 7, q = bid >> 3;
  const int bn = (xcd << 2) | (q >> 4);
  const int bm = q & 15;

  const int laneRow = lane & 15, lane16 = lane >> 4;
  const int lr7 = laneRow & 7;
  const int colE0 = (lane16 ^ lr7) << 3;         // elem offset within row, kk=0
  const int colE1 = ((4 + lane16) ^ lr7) << 3;   // kk=1

  // Staging: per inst, lane l -> LDS row +(l>>3), phys slot (l&7); slot s at row r
  // holds logical chunk s^(r&7) -> pre-swizzled global source chunk.
  const int srow = w * 8 + (lane >> 3);
  const int chunkOff = ((lane & 7) ^ (lane >> 3)) << 3;
  const ushort* aSrc = A + (size_t)(bm * 256 + srow) * 4096 + chunkOff;
  const ushort* bSrc = Wp + (size_t)(bn * 256 + srow) * 4096 + chunkOff;
  const int aDstW = w * 512;           // + buf + jj*4096
  const int bDstW = 16384 + w * 512;

  const int aBase = (wm * 64 + laneRow) * 64;           // + buf + miq*8192 + m*1024 + colE
  const int bBase = 16384 + (wn * 32 + laneRow) * 64;   // + buf + (ni>>1)*8192 + (ni&1)*1024 + colE

  f32x4 acc[8][4];
#pragma unroll
  for (int i = 0; i < 8; i++)
#pragma unroll
    for (int j = 0; j < 4; j++) acc[i][j] = (f32x4){0.f, 0.f, 0.f, 0.f};

  // Prologue: stage T0 (A0,B0,B1,A1) then T1 (same order), 16 insts/wave.
  STG(aSrc, 0, 0, aDstW); STG(aSrc, 1, 0, aDstW);
  STG(bSrc, 0, 0, bDstW); STG(bSrc, 1, 0, bDstW);
  STG(bSrc, 2, 0, bDstW); STG(bSrc, 3, 0, bDstW);
  STG(aSrc, 2, 0, aDstW); STG(aSrc, 3, 0, aDstW);
  STG(aSrc, 0, 64, 32768 + aDstW); STG(aSrc, 1, 64, 32768 + aDstW);
  STG(bSrc, 0, 64, 32768 + bDstW); STG(bSrc, 1, 64, 32768 + bDstW);
  STG(bSrc, 2, 64, 32768 + bDstW); STG(bSrc, 3, 64, 32768 + bDstW);
  STG(aSrc, 2, 64, 32768 + aDstW); STG(aSrc, 3, 64, 32768 + aDstW);
  asm volatile("s_waitcnt vmcnt(10)" ::: "memory");  // T0: A0,B0,B1 resident
  __builtin_amdgcn_s_barrier();
  __builtin_amdgcn_sched_barrier(0);

  bf16x8 af0A[4][2], af0B[4][2], bf01A[4][2], bf01B[4][2], af1_[4][2], bf23_[4][2];
  // Pre-read T0 ph0 fragments (af0 miq0 + bf01) from buf0.
#pragma unroll
  for (int m = 0; m < 4; ++m) {
    af0A[m][0] = *(const bf16x8*)&smem[aBase + m * 1024 + colE0];
    af0A[m][1] = *(const bf16x8*)&smem[aBase + m * 1024 + colE1];
  }
#pragma unroll
  for (int n = 0; n < 2; ++n) {
    bf01A[n][0] = *(const bf16x8*)&smem[bBase + n * 1024 + colE0];
    bf01A[n][1] = *(const bf16x8*)&smem[bBase + n * 1024 + colE1];
  }

#pragma unroll 1
  for (int t = 0; t < 32; ++t) {
    const int Ta = 2 * t, Tb = 2 * t + 1;
    TILE_BODY(Ta, 0,     af0A, bf01A, af0B, bf01B);
    TILE_BODY(Tb, 32768, af0B, bf01B, af0A, bf01A);
  }

  // Fused LSTM epilogue: acc[mi][gate][rr] register-local per (row, hcol).
  const int hcol = bn * 64 + wn * 16 + laneRow;
  const float bI = bii[hcol] + bhi[hcol];
  const float bF = bif_[hcol] + bhf[hcol];
  const float bG = big_[hcol] + bhg[hcol];
  const float bO = bio_[hcol] + bho[hcol];
#pragma unroll
  for (int mi = 0; mi < 8; ++mi) {
    const int rowBase = bm * 256 + (mi >> 2) * 128 + wm * 64 + (mi & 3) * 16 + lane16 * 4;
#pragma unroll
    for (int rr = 0; rr < 4; ++rr) {
      const int row = rowBase + rr;
      const float ii = acc[mi][0][rr] + bI;
      const float ff = acc[mi][1][rr] + bF;
      const float gg = acc[mi][2][rr] + bG;
      const float oo = acc[mi][3][rr] + bO;
      const float iv = 1.f / (1.f + __expf(-ii));
      const float fv = 1.f / (1.f + __expf(-ff));
      const float gv = tanhf(gg);
      const float ov = 1.f / (1.f + __expf(-oo));
      const float cv = c[(size_t)row * 2048 + hcol];
      const float cn = fv * cv + iv * gv;
      const float hn = ov * tanhf(cn);
      out[(size_t)row * 2048 + hcol] = hn;
      out[(size_t)8388608 + (size_t)row * 2048 + hcol] = cn;
    }
  }
}

extern "C" void kernel_launch(void* const* d_in, const int* in_sizes, int n_in,
                              void* d_out, int out_size, void* d_ws, size_t ws_size,
                              hipStream_t stream) {
  const float* x = (const float*)d_in[0];
  const float* h = (const float*)d_in[1];
  const float* c = (const float*)d_in[2];
  const float* Wii = (const float*)d_in[3];  const float* bii = (const float*)d_in[4];
  const float* Wif = (const float*)d_in[5];  const float* bif_ = (const float*)d_in[6];
  const float* Wig = (const float*)d_in[7];  const float* big_ = (const float*)d_in[8];
  const float* Wio = (const float*)d_in[9];  const float* bio_ = (const float*)d_in[10];
  const float* Whi = (const float*)d_in[11]; const float* bhi = (const float*)d_in[12];
  const float* Whf = (const float*)d_in[13]; const float* bhf = (const float*)d_in[14];
  const float* Whg = (const float*)d_in[15]; const float* bhg = (const float*)d_in[16];
  const float* Who = (const float*)d_in[17]; const float* bho = (const float*)d_in[18];

  ushort* Abf = (ushort*)d_ws;                    // 4096*4096 bf16
  ushort* Wpk = Abf + (size_t)4096 * 4096;        // 8192*4096 bf16
  float* out = (float*)d_out;

  pack_a_kernel<<<2048, 256, 0, stream>>>((const float4*)x, (const float4*)h, (ushort4*)Abf);
  pack_w_kernel<<<2048, 256, 0, stream>>>(Wii, Wif, Wig, Wio, Whi, Whf, Whg, Who, (ushort4*)Wpk);
  lstm_gemm_kernel<<<512, 512, 0, stream>>>(Abf, Wpk, c,
                                            bii, bif_, big_, bio_, bhi, bhf, bhg, bho, out);
}

// Round 6
// 315.697 us; speedup vs baseline: 4.0955x; 4.0955x over previous
//
#include <hip/hip_runtime.h>
#include <stdint.h>

typedef __attribute__((ext_vector_type(4))) float f32x4;
typedef __attribute__((ext_vector_type(8))) short bf16x8;

#define MFMA_BF16 __builtin_amdgcn_mfma_f32_16x16x32_bf16

__device__ __forceinline__ unsigned short f2bf(float f) {
  union { float f; uint32_t u; } a; a.f = f;
  uint32_t u = a.u;
  uint32_t r = (u + 0x7FFFu + ((u >> 16) & 1u)) >> 16;
  return (unsigned short)r;
}

// Pack [x | h] -> bf16 A[4096][4096] row-major (K = IN(2048) then H(2048))
__global__ void pack_a_kernel(const float4* __restrict__ x, const float4* __restrict__ hh,
                              ushort4* __restrict__ A) {
  const int total = 4096 * 1024;
  for (int q = blockIdx.x * blockDim.x + threadIdx.x; q < total; q += gridDim.x * blockDim.x) {
    int row = q >> 10, cq = q & 1023;
    float4 v = (cq < 512) ? x[row * 512 + cq] : hh[row * 512 + (cq - 512)];
    ushort4 o; o.x = f2bf(v.x); o.y = f2bf(v.y); o.z = f2bf(v.z); o.w = f2bf(v.w);
    A[q] = o;
  }
}

// Pack 8 weight mats -> bf16 Wp[8192][4096].
// Packed row p: bn=p>>8, r=p&255; half=r>>7, wn=(r>>5)&3, glow=(r>>4)&1, hlow=r&15
//   gate g = half*2+glow ; hcol H = bn*64 + wn*16 + hlow
// cols 0..2047 = Wx_g[H][:], 2048..4095 = Wh_g[H][:]
__global__ void pack_w_kernel(const float* __restrict__ Wii, const float* __restrict__ Wif,
                              const float* __restrict__ Wig, const float* __restrict__ Wio,
                              const float* __restrict__ Whi, const float* __restrict__ Whf,
                              const float* __restrict__ Whg, const float* __restrict__ Who,
                              ushort4* __restrict__ Wp) {
  const int total = 8192 * 1024;
  for (int q = blockIdx.x * blockDim.x + threadIdx.x; q < total; q += gridDim.x * blockDim.x) {
    int p = q >> 10, kq = q & 1023;
    int r = p & 255;
    int g = ((r >> 7) << 1) | ((r >> 4) & 1);
    int H = ((p >> 8) << 6) | (((r >> 5) & 3) << 4) | (r & 15);
    const float* src;
    if (kq < 512) src = (g == 0) ? Wii : (g == 1) ? Wif : (g == 2) ? Wig : Wio;
    else          src = (g == 0) ? Whi : (g == 1) ? Whf : (g == 2) ? Whg : Who;
    const float4 v = *(const float4*)&src[(size_t)H * 2048 + ((kq & 511) << 2)];
    ushort4 o; o.x = f2bf(v.x); o.y = f2bf(v.y); o.z = f2bf(v.z); o.w = f2bf(v.w);
    Wp[q] = o;
  }
}

// 256x256 tile, BK=64, 8 waves (2Mx4N), per-wave 128x64.
// FREE-DRIFT tile: stage next tile at top (into the other buffer - no mid-tile
// WAR hazard), compiler-scheduled ds_read/MFMA interleave (auto counted lgkmcnt),
// ONE sync point per tile: vmcnt(0); s_barrier; sched_barrier(0).
// T2 XOR-swizzle, bn-major XCD mapping, fused LSTM epilogue.
#define STG(srcbase, jj, koff, dstE)                                                        \
  __builtin_amdgcn_global_load_lds(                                                        \
      (const __attribute__((address_space(1))) void*)((srcbase) + (size_t)(jj)*262144 + (koff)), \
      (__attribute__((address_space(3))) void*)(&smem[(dstE) + (jj)*4096]), 16, 0, 0)

__global__ __launch_bounds__(512, 2)
void lstm_gemm_kernel(const ushort* __restrict__ A, const ushort* __restrict__ Wp,
                      const float* __restrict__ c,
                      const float* __restrict__ bii, const float* __restrict__ bif_,
                      const float* __restrict__ big_, const float* __restrict__ bio_,
                      const float* __restrict__ bhi, const float* __restrict__ bhf,
                      const float* __restrict__ bhg, const float* __restrict__ bho,
                      float* __restrict__ out) {
  __shared__ ushort smem[65536];  // 2 bufs x (A 256x64 + B 256x64) bf16 = 128 KiB
  const int tid = threadIdx.x;
  const int lane = tid & 63, w = tid >> 6;
  const int wm = w >> 2, wn = w & 3;

  // bn-major XCD mapping: XCD x owns bn in [x*4, x*4+4) x all 16 bm.
  const int bid = blockIdx.x;
  const int xcd = bid & 7, q = bid >> 3;
  const int bn = (xcd << 2) | (q >> 4);
  const int bm = q & 15;

  const int laneRow = lane & 15, lane16 = lane >> 4;
  const int lr7 = laneRow & 7;
  const int colE0 = (lane16 ^ lr7) << 3;         // elem offset within row, kk=0
  const int colE1 = ((4 + lane16) ^ lr7) << 3;   // kk=1

  // Staging: per inst, lane l -> LDS row +(l>>3), phys slot (l&7); slot s at row r
  // holds logical chunk s^(r&7) -> pre-swizzled global source chunk.
  const int srow = w * 8 + (lane >> 3);
  const int chunkOff = ((lane & 7) ^ (lane >> 3)) << 3;
  const ushort* aSrc = A + (size_t)(bm * 256 + srow) * 4096 + chunkOff;
  const ushort* bSrc = Wp + (size_t)(bn * 256 + srow) * 4096 + chunkOff;
  const int aDstW = w * 512;           // + buf + jj*4096
  const int bDstW = 16384 + w * 512;

  const int aBase = (wm * 64 + laneRow) * 64;           // + buf + miq*8192 + m*1024 + colE
  const int bBase = 16384 + (wn * 32 + laneRow) * 64;   // + buf + (ni>>1)*8192 + (ni&1)*1024 + colE

  f32x4 acc[8][4];
#pragma unroll
  for (int i = 0; i < 8; i++)
#pragma unroll
    for (int j = 0; j < 4; j++) acc[i][j] = (f32x4){0.f, 0.f, 0.f, 0.f};

  // Prologue: stage T0 into buf0.
  STG(aSrc, 0, 0, aDstW); STG(aSrc, 1, 0, aDstW);
  STG(aSrc, 2, 0, aDstW); STG(aSrc, 3, 0, aDstW);
  STG(bSrc, 0, 0, bDstW); STG(bSrc, 1, 0, bDstW);
  STG(bSrc, 2, 0, bDstW); STG(bSrc, 3, 0, bDstW);
  asm volatile("s_waitcnt vmcnt(0)" ::: "memory");
  __builtin_amdgcn_s_barrier();
  __builtin_amdgcn_sched_barrier(0);

#pragma unroll 1
  for (int T = 0; T < 64; ++T) {
    const int bufE = (T & 1) << 15;
    const int obufE = bufE ^ 32768;
    const int kS = (T + 1) << 6;

    // Stage ALL of tile T+1 into the other buffer (read last at T-1; its
    // boundary barrier already passed -> no WAR hazard anywhere in this tile).
    if (T < 63) {
      STG(aSrc, 0, kS, obufE + aDstW); STG(aSrc, 1, kS, obufE + aDstW);
      STG(aSrc, 2, kS, obufE + aDstW); STG(aSrc, 3, kS, obufE + aDstW);
      STG(bSrc, 0, kS, obufE + bDstW); STG(bSrc, 1, kS, obufE + bDstW);
      STG(bSrc, 2, kS, obufE + bDstW); STG(bSrc, 3, kS, obufE + bDstW);
    }

    bf16x8 af[4][2], b01[2][2], b23[2][2];
    // quadrant 00: af(miq0) x b01
#pragma unroll
    for (int m = 0; m < 4; ++m) {
      af[m][0] = *(const bf16x8*)&smem[bufE + aBase + m * 1024 + colE0];
      af[m][1] = *(const bf16x8*)&smem[bufE + aBase + m * 1024 + colE1];
    }
#pragma unroll
    for (int n = 0; n < 2; ++n) {
      b01[n][0] = *(const bf16x8*)&smem[bufE + bBase + n * 1024 + colE0];
      b01[n][1] = *(const bf16x8*)&smem[bufE + bBase + n * 1024 + colE1];
    }
    __builtin_amdgcn_s_setprio(1);
#pragma unroll
    for (int m = 0; m < 4; ++m)
#pragma unroll
      for (int n = 0; n < 2; ++n) {
        acc[m][n] = MFMA_BF16(af[m][0], b01[n][0], acc[m][n], 0, 0, 0);
        acc[m][n] = MFMA_BF16(af[m][1], b01[n][1], acc[m][n], 0, 0, 0);
      }
    __builtin_amdgcn_s_setprio(0);

    // quadrant 01: af(miq0) x b23
#pragma unroll
    for (int n = 0; n < 2; ++n) {
      b23[n][0] = *(const bf16x8*)&smem[bufE + bBase + 8192 + n * 1024 + colE0];
      b23[n][1] = *(const bf16x8*)&smem[bufE + bBase + 8192 + n * 1024 + colE1];
    }
    __builtin_amdgcn_s_setprio(1);
#pragma unroll
    for (int m = 0; m < 4; ++m)
#pragma unroll
      for (int n = 0; n < 2; ++n) {
        acc[m][2 + n] = MFMA_BF16(af[m][0], b23[n][0], acc[m][2 + n], 0, 0, 0);
        acc[m][2 + n] = MFMA_BF16(af[m][1], b23[n][1], acc[m][2 + n], 0, 0, 0);
      }
    __builtin_amdgcn_s_setprio(0);

    // quadrant 10: af(miq1) x b01
#pragma unroll
    for (int m = 0; m < 4; ++m) {
      af[m][0] = *(const bf16x8*)&smem[bufE + aBase + 8192 + m * 1024 + colE0];
      af[m][1] = *(const bf16x8*)&smem[bufE + aBase + 8192 + m * 1024 + colE1];
    }
    __builtin_amdgcn_s_setprio(1);
#pragma unroll
    for (int m = 0; m < 4; ++m)
#pragma unroll
      for (int n = 0; n < 2; ++n) {
        acc[4 + m][n] = MFMA_BF16(af[m][0], b01[n][0], acc[4 + m][n], 0, 0, 0);
        acc[4 + m][n] = MFMA_BF16(af[m][1], b01[n][1], acc[4 + m][n], 0, 0, 0);
      }
    __builtin_amdgcn_s_setprio(0);

    // quadrant 11: af(miq1) x b23
    __builtin_amdgcn_s_setprio(1);
#pragma unroll
    for (int m = 0; m < 4; ++m)
#pragma unroll
      for (int n = 0; n < 2; ++n) {
        acc[4 + m][2 + n] = MFMA_BF16(af[m][0], b23[n][0], acc[4 + m][2 + n], 0, 0, 0);
        acc[4 + m][2 + n] = MFMA_BF16(af[m][1], b23[n][1], acc[4 + m][2 + n], 0, 0, 0);
      }
    __builtin_amdgcn_s_setprio(0);

    // Single sync point per tile: next tile's data resident + all waves done
    // reading this buffer (every ds_read has a dependent MFMA above).
    asm volatile("s_waitcnt vmcnt(0)" ::: "memory");
    __builtin_amdgcn_s_barrier();
    __builtin_amdgcn_sched_barrier(0);
  }

  // Fused LSTM epilogue: acc[mi][gate][rr] register-local per (row, hcol).
  const int hcol = bn * 64 + wn * 16 + laneRow;
  const float bI = bii[hcol] + bhi[hcol];
  const float bF = bif_[hcol] + bhf[hcol];
  const float bG = big_[hcol] + bhg[hcol];
  const float bO = bio_[hcol] + bho[hcol];
#pragma unroll
  for (int mi = 0; mi < 8; ++mi) {
    const int rowBase = bm * 256 + (mi >> 2) * 128 + wm * 64 + (mi & 3) * 16 + lane16 * 4;
#pragma unroll
    for (int rr = 0; rr < 4; ++rr) {
      const int row = rowBase + rr;
      const float ii = acc[mi][0][rr] + bI;
      const float ff = acc[mi][1][rr] + bF;
      const float gg = acc[mi][2][rr] + bG;
      const float oo = acc[mi][3][rr] + bO;
      const float iv = 1.f / (1.f + __expf(-ii));
      const float fv = 1.f / (1.f + __expf(-ff));
      const float gv = tanhf(gg);
      const float ov = 1.f / (1.f + __expf(-oo));
      const float cv = c[(size_t)row * 2048 + hcol];
      const float cn = fv * cv + iv * gv;
      const float hn = ov * tanhf(cn);
      out[(size_t)row * 2048 + hcol] = hn;
      out[(size_t)8388608 + (size_t)row * 2048 + hcol] = cn;
    }
  }
}

extern "C" void kernel_launch(void* const* d_in, const int* in_sizes, int n_in,
                              void* d_out, int out_size, void* d_ws, size_t ws_size,
                              hipStream_t stream) {
  const float* x = (const float*)d_in[0];
  const float* h = (const float*)d_in[1];
  const float* c = (const float*)d_in[2];
  const float* Wii = (const float*)d_in[3];  const float* bii = (const float*)d_in[4];
  const float* Wif = (const float*)d_in[5];  const float* bif_ = (const float*)d_in[6];
  const float* Wig = (const float*)d_in[7];  const float* big_ = (const float*)d_in[8];
  const float* Wio = (const float*)d_in[9];  const float* bio_ = (const float*)d_in[10];
  const float* Whi = (const float*)d_in[11]; const float* bhi = (const float*)d_in[12];
  const float* Whf = (const float*)d_in[13]; const float* bhf = (const float*)d_in[14];
  const float* Whg = (const float*)d_in[15]; const float* bhg = (const float*)d_in[16];
  const float* Who = (const float*)d_in[17]; const float* bho = (const float*)d_in[18];

  ushort* Abf = (ushort*)d_ws;                    // 4096*4096 bf16
  ushort* Wpk = Abf + (size_t)4096 * 4096;        // 8192*4096 bf16
  float* out = (float*)d_out;

  pack_a_kernel<<<2048, 256, 0, stream>>>((const float4*)x, (const float4*)h, (ushort4*)Abf);
  pack_w_kernel<<<2048, 256, 0, stream>>>(Wii, Wif, Wig, Wio, Whi, Whf, Whg, Who, (ushort4*)Wpk);
  lstm_gemm_kernel<<<512, 512, 0, stream>>>(Abf, Wpk, c,
                                            bii, bif_, big_, bio_, bhi, bhf, bhg, bho, out);
}